// Round 4
// baseline (1280.416 us; speedup 1.0000x reference)
//
#include <hip/hip_runtime.h>
#include <math.h>

// ---------------------------------------------------------------------------
// ConflictAwareResidualRouter  (B=4, S=2048, D=4096, H=128, RH=64, NA=4, K=2)
//
// Kernel A (gates_kernel): per-token gate computation, fully fused:
//   feat = relu(h @ rel_proj_w + b)           [8192x4096]x[4096x64]
//   rel  = sigmoid(feat @ rel_heads_w + b)    tiny
//   hid  = relu([h,rel,conf] @ gate_w1 + b)   [8192x4104]x[4104x128]
//   logits = hid @ gate_w2 + b                128x6
//   top-2 mask over adapter logits, softmax -> 5 coefs/token into d_ws
// Both big GEMMs share ONE streaming pass over h (the [4096x64] rel-proj and
// [4096x128] gate columns fuse into a 192-wide output tile); rel/conf rows of
// gate_w1 are added in the per-token epilogue.
// h tile is stored transposed in LDS with a rotation swizzle
//   col' = (tok + 4*(row&7)) & 31
// so the inner-loop float4 read is 16B-aligned AND bank-conflict-free
// (8 distinct 16B chunks covering all 32 banks, 8-way broadcast); the
// scalar staging writes degrade to 8-way conflict (negligible vs compute).
// Register double-buffering: chunk k+1's global loads (14 float4/thread)
// issue while chunk k computes (grid == 256 -> 1 block/CU, ILP-only hiding).
//
// Kernel B (combine_kernel): out = c_static*static_delta + sum_n c_n*res_n.
// Exactly 2 of 4 adapter coefs are nonzero per token -> skip 2 of 4 residual
// reads (uniform per token => no divergence within a wave).
// Traffic: 134 (sd) + 2*134 (kept res) + 134 (write) ~ 671 MB.
// ---------------------------------------------------------------------------

constexpr int D      = 4096;
constexpr int RH     = 64;
constexpr int HG     = 128;
constexpr int NA     = 4;
constexpr int NOUT   = RH + HG;     // 192 fused GEMM outputs
constexpr int TOKENS = 4 * 2048;    // 8192
constexpr int M_BLK  = 32;          // tokens per block
constexpr int KC     = 64;          // K chunk
constexpr int NCHUNK = D / KC;      // 64

__global__ __launch_bounds__(256, 1) void gates_kernel(
    const float* __restrict__ h,
    const float* __restrict__ conflict,
    const float* __restrict__ rpw, const float* __restrict__ rpb,
    const float* __restrict__ rhw, const float* __restrict__ rhb,
    const float* __restrict__ gw1, const float* __restrict__ gb1,
    const float* __restrict__ gw2, const float* __restrict__ gb2,
    float* __restrict__ coef)
{
    __shared__ float smem[KC * M_BLK + KC * NOUT];  // 8KB + 48KB = 56KB
    float* hT = smem;                 // [row=k][col' swizzled], flat 64*32
    float* wT = smem + KC * M_BLK;    // flat [k*192 + col]

    const int tid  = threadIdx.x;
    const int tok0 = blockIdx.x * M_BLK;
    const int tg   = tid & 7;    // token group: tokens tg*4 .. tg*4+3
    const int og   = tid >> 3;   // output group: cols og*6 .. og*6+5

    float4 hreg[2];              // prefetch: h      (2 float4 / thread)
    float4 wreg[12];             // prefetch: W tile (12 float4 / thread)

    auto load_chunk = [&](int kc) {
        const int k0 = kc * KC;
#pragma unroll
        for (int r = 0; r < 2; ++r) {
            int q = tid + 256 * r;           // 0..511
            int tok = q >> 4, kq = q & 15;   // 16 lanes span 256B: coalesced
            hreg[r] = *reinterpret_cast<const float4*>(
                h + (size_t)(tok0 + tok) * D + k0 + kq * 4);
        }
#pragma unroll
        for (int r = 0; r < 12; ++r) {
            int q = tid + 256 * r;           // 0..3071
            int f = q * 4;                   // packed [k][0..191] offset
            int k = f / NOUT;                // magic-mul
            int c = f - k * NOUT;            // mult of 4; never straddles 64
            const float* src = (c < RH)
                ? (rpw + (size_t)(k0 + k) * RH + c)
                : (gw1 + (size_t)(k0 + k) * HG + (c - RH));
            wreg[r] = *reinterpret_cast<const float4*>(src);
        }
    };
    auto store_chunk = [&]() {
#pragma unroll
        for (int r = 0; r < 2; ++r) {
            int q = tid + 256 * r;
            int tok = q >> 4, kq = q & 15;
            float v[4] = {hreg[r].x, hreg[r].y, hreg[r].z, hreg[r].w};
#pragma unroll
            for (int j = 0; j < 4; ++j) {
                int row = kq * 4 + j;                    // k within chunk
                int col = (tok + 4 * (row & 7)) & 31;    // rotation swizzle
                hT[row * M_BLK + col] = v[j];
            }
        }
#pragma unroll
        for (int r = 0; r < 12; ++r)
            *reinterpret_cast<float4*>(wT + (size_t)(tid + 256 * r) * 4) = wreg[r];
    };

    float acc[4][6];
#pragma unroll
    for (int i = 0; i < 4; ++i)
#pragma unroll
        for (int j = 0; j < 6; ++j) acc[i][j] = 0.f;

    load_chunk(0);
    for (int kc = 0; kc < NCHUNK; ++kc) {
        __syncthreads();                 // previous compute done reading LDS
        store_chunk();
        if (kc + 1 < NCHUNK) load_chunk(kc + 1);   // overlap w/ compute below
        __syncthreads();                 // tile ready

#pragma unroll 2
        for (int k = 0; k < KC; ++k) {
            // swizzled, 16B-aligned: tokens tg*4..tg*4+3 at row k
            const float4 hv = *reinterpret_cast<const float4*>(
                &hT[k * M_BLK + ((tg * 4 + 4 * (k & 7)) & 31)]);
            const float* wr = wT + k * NOUT + og * 6;
            float2 w0 = *reinterpret_cast<const float2*>(wr + 0);
            float2 w1 = *reinterpret_cast<const float2*>(wr + 2);
            float2 w2 = *reinterpret_cast<const float2*>(wr + 4);
            const float hh[4] = {hv.x, hv.y, hv.z, hv.w};
            const float ww[6] = {w0.x, w0.y, w1.x, w1.y, w2.x, w2.y};
#pragma unroll
            for (int i = 0; i < 4; ++i)
#pragma unroll
                for (int j = 0; j < 6; ++j)
                    acc[i][j] = fmaf(hh[i], ww[j], acc[i][j]);
        }
    }
    __syncthreads();                     // LDS dead -> reuse for epilogue

    // park accumulators in LDS for the per-token epilogue (overlay on hT/wT)
    float (*ob)[NOUT + 1] = reinterpret_cast<float (*)[NOUT + 1]>(smem);
#pragma unroll
    for (int i = 0; i < 4; ++i)
#pragma unroll
        for (int j = 0; j < 6; ++j)
            ob[tg * 4 + i][og * 6 + j] = acc[i][j];
    __syncthreads();

    if (tid < M_BLK) {
        const int t  = tid;
        const int gt = tok0 + t;

        // rel = sigmoid(relu(feat) @ rhw + rhb)
        float ra[NA] = {0.f, 0.f, 0.f, 0.f};
        for (int j = 0; j < RH; ++j) {
            float f = ob[t][j] + rpb[j];
            f = f > 0.f ? f : 0.f;
#pragma unroll
            for (int a = 0; a < NA; ++a) ra[a] = fmaf(f, rhw[j * NA + a], ra[a]);
        }
        float rel[NA], cf[NA];
#pragma unroll
        for (int a = 0; a < NA; ++a) {
            rel[a] = 1.f / (1.f + expf(-(ra[a] + rhb[a])));
            cf[a]  = conflict[(size_t)gt * NA + a];
        }

        // hid = relu(hid_pre + rel/conf rows of gate_w1 + b1); logits = hid@gw2+b2
        float lg[6] = {0.f, 0.f, 0.f, 0.f, 0.f, 0.f};
        for (int i = 0; i < HG; ++i) {
            float v = ob[t][RH + i] + gb1[i];
#pragma unroll
            for (int a = 0; a < NA; ++a)
                v = fmaf(rel[a], gw1[(size_t)(D + a) * HG + i], v);
#pragma unroll
            for (int a = 0; a < NA; ++a)
                v = fmaf(cf[a], gw1[(size_t)(D + NA + a) * HG + i], v);
            v = v > 0.f ? v : 0.f;
#pragma unroll
            for (int c = 0; c < 6; ++c) lg[c] = fmaf(v, gw2[i * 6 + c], lg[c]);
        }
#pragma unroll
        for (int c = 0; c < 6; ++c) lg[c] += gb2[c];   // TEMPERATURE == 1

        // top-2 of adapter logits lg[2..5]; strict > keeps lax.top_k tie order
        int i1 = 0;
#pragma unroll
        for (int a = 1; a < NA; ++a) if (lg[2 + a] > lg[2 + i1]) i1 = a;
        int i2 = (i1 == 0) ? 1 : 0;
#pragma unroll
        for (int a = 0; a < NA; ++a)
            if (a != i1 && lg[2 + a] > lg[2 + i2]) i2 = a;

        // softmax over {l0, l1, kept adapters}; dropped adapters are -inf
        float m  = fmaxf(fmaxf(lg[0], lg[1]), fmaxf(lg[2 + i1], lg[2 + i2]));
        float e0 = expf(lg[0] - m), e1 = expf(lg[1] - m);
        float ea = expf(lg[2 + i1] - m), eb = expf(lg[2 + i2] - m);
        float inv = 1.f / (e0 + e1 + ea + eb);

        float out5[5] = {e1 * inv, 0.f, 0.f, 0.f, 0.f};   // gates[...,1]
        out5[1 + i1] = ea * inv;
        out5[1 + i2] = eb * inv;
        float* cp = coef + (size_t)gt * 8;
#pragma unroll
        for (int s = 0; s < 5; ++s) cp[s] = out5[s];
    }
}

__global__ __launch_bounds__(256) void combine_kernel(
    const float* __restrict__ sd,
    const float* __restrict__ ar,
    const float* __restrict__ coef,
    float* __restrict__ out)
{
    const size_t NT4 = (size_t)TOKENS * (D / 4);   // 8,388,608 float4s
    const size_t stride = (size_t)gridDim.x * blockDim.x;
    const float4* sd4  = reinterpret_cast<const float4*>(sd);
    const float4* ar4  = reinterpret_cast<const float4*>(ar);
    float4*       out4 = reinterpret_cast<float4*>(out);

    for (size_t v = (size_t)blockIdx.x * blockDim.x + threadIdx.x;
         v < NT4; v += stride) {
        const int tok = (int)(v >> 10);            // D/4 = 1024 float4s/token
        const float* cp = coef + (size_t)tok * 8;
        const float cs = cp[0];
        float4 s = sd4[v];
        float4 o;
        o.x = cs * s.x; o.y = cs * s.y; o.z = cs * s.z; o.w = cs * s.w;
#pragma unroll
        for (int n = 0; n < NA; ++n) {
            const float cn = cp[1 + n];
            if (cn != 0.f) {                       // uniform per token
                float4 r = ar4[(size_t)n * NT4 + v];
                o.x = fmaf(cn, r.x, o.x); o.y = fmaf(cn, r.y, o.y);
                o.z = fmaf(cn, r.z, o.z); o.w = fmaf(cn, r.w, o.w);
            }
        }
        out4[v] = o;
    }
}

extern "C" void kernel_launch(void* const* d_in, const int* in_sizes, int n_in,
                              void* d_out, int out_size, void* d_ws, size_t ws_size,
                              hipStream_t stream) {
    const float* h   = (const float*)d_in[0];
    const float* sd  = (const float*)d_in[1];
    const float* ar  = (const float*)d_in[2];
    const float* cs  = (const float*)d_in[3];
    const float* rpw = (const float*)d_in[4];
    const float* rpb = (const float*)d_in[5];
    const float* rhw = (const float*)d_in[6];
    const float* rhb = (const float*)d_in[7];
    const float* gw1 = (const float*)d_in[8];
    const float* gb1 = (const float*)d_in[9];
    const float* gw2 = (const float*)d_in[10];
    const float* gb2 = (const float*)d_in[11];

    float* coef = (float*)d_ws;            // 8192 tokens * 8 floats = 256 KB
    float* out  = (float*)d_out;

    hipLaunchKernelGGL(gates_kernel, dim3(TOKENS / M_BLK), dim3(256), 0, stream,
                       h, cs, rpw, rpb, rhw, rhb, gw1, gb1, gw2, gb2, coef);
    hipLaunchKernelGGL(combine_kernel, dim3(2048), dim3(256), 0, stream,
                       sd, ar, coef, out);
}

// Round 7
// 1194.790 us; speedup vs baseline: 1.0717x; 1.0717x over previous
//
#include <hip/hip_runtime.h>
#include <math.h>

// ---------------------------------------------------------------------------
// ConflictAwareResidualRouter  (B=4, S=2048, D=4096, H=128, RH=64, NA=4, K=2)
//
// R4 counters: gates 531us, VALUBusy 24.5%, Occupancy 11.4% -> latency-bound
// at 1 block/CU (grid 256). Fix: split-K x4 (grid 1024, KC 64->32, LDS 28KB,
// launch_bounds(256,4)) => 4 blocks/CU, 16 waves/CU. Inner loop unchanged.
//
// gates_partial : per (token-block, k-slice) partial 192-wide GEMM outputs,
//                 written fp32 to d_out scratch (combine overwrites d_out).
// gates_epilogue: sum 4 slices (fixed order), rel/sigmoid, gate MLP, top-2
//                 mask + softmax -> 5 coefs/token into d_ws.
// combine       : out = c_static*sd + sum_n c_n*res_n; 2 of 4 adapters
//                 skipped per token (uniform per wave).
// ---------------------------------------------------------------------------

constexpr int D      = 4096;
constexpr int RH     = 64;
constexpr int HG     = 128;
constexpr int NA     = 4;
constexpr int NOUT   = RH + HG;     // 192
constexpr int TOKENS = 4 * 2048;    // 8192
constexpr int M_BLK  = 32;          // tokens per block
constexpr int NSLICE = 4;           // K slices
constexpr int KSL    = D / NSLICE;  // 1024
constexpr int KC     = 32;          // K chunk
constexpr int NCH    = KSL / KC;    // 32 chunks per slice

__global__ __launch_bounds__(256, 4) void gates_partial(
    const float* __restrict__ h,
    const float* __restrict__ rpw,
    const float* __restrict__ gw1,
    float* __restrict__ part)           // [NSLICE][TOKENS][NOUT] in d_out
{
    __shared__ float smem[KC * M_BLK + KC * NOUT];   // 1024+6144 fl = 28KB
    float* hT = smem;                  // [row=k][col' swizzled], flat 32*32
    float* wT = smem + KC * M_BLK;     // flat [k*192 + col]

    const int tid   = threadIdx.x;
    const int bt    = blockIdx.x >> 2;         // token block 0..255
    const int sl    = blockIdx.x & 3;          // k slice    0..3
    const int tok0  = bt * M_BLK;
    const int kbase = sl * KSL;
    const int tg    = tid & 7;                 // tokens tg*4..tg*4+3
    const int og    = tid >> 3;                // cols og*6..og*6+5

    float4 hreg;                 // 1 float4 / thread  (32x32 h tile)
    float4 wreg[6];              // 6 float4 / thread  (32x192 W tile)

    auto load_chunk = [&](int kc) {
        const int k0 = kbase + kc * KC;
        {   // h: 8 lanes span 128B contiguous -> coalesced
            int tok = tid >> 3, kq = tid & 7;
            hreg = *reinterpret_cast<const float4*>(
                h + (size_t)(tok0 + tok) * D + k0 + kq * 4);
        }
#pragma unroll
        for (int r = 0; r < 6; ++r) {
            int q = tid + 256 * r;             // 0..1535
            int f = q * 4;                     // packed [k][0..191]
            int k = f / NOUT;                  // magic-mul
            int c = f - k * NOUT;              // mult of 4; never straddles 64
            const float* src = (c < RH)
                ? (rpw + (size_t)(k0 + k) * RH + c)
                : (gw1 + (size_t)(k0 + k) * HG + (c - RH));
            wreg[r] = *reinterpret_cast<const float4*>(src);
        }
    };
    auto store_chunk = [&]() {
        {
            int tok = tid >> 3, kq = tid & 7;
            float v[4] = {hreg.x, hreg.y, hreg.z, hreg.w};
#pragma unroll
            for (int j = 0; j < 4; ++j) {
                int row = kq * 4 + j;                   // 0..31
                int col = (tok + 4 * (row & 7)) & 31;   // rotation swizzle
                hT[row * M_BLK + col] = v[j];
            }
        }
#pragma unroll
        for (int r = 0; r < 6; ++r)
            *reinterpret_cast<float4*>(wT + (size_t)(tid + 256 * r) * 4) = wreg[r];
    };

    float acc[4][6];
#pragma unroll
    for (int i = 0; i < 4; ++i)
#pragma unroll
        for (int j = 0; j < 6; ++j) acc[i][j] = 0.f;

    load_chunk(0);
    for (int kc = 0; kc < NCH; ++kc) {
        __syncthreads();
        store_chunk();
        if (kc + 1 < NCH) load_chunk(kc + 1);
        __syncthreads();
#pragma unroll 2
        for (int k = 0; k < KC; ++k) {
            // swizzled, 16B-aligned (base is mult of 4, no mod-32 wrap)
            const float4 hv = *reinterpret_cast<const float4*>(
                &hT[k * M_BLK + ((tg * 4 + 4 * (k & 7)) & 31)]);
            const float* wr = wT + k * NOUT + og * 6;
            float2 w0 = *reinterpret_cast<const float2*>(wr + 0);
            float2 w1 = *reinterpret_cast<const float2*>(wr + 2);
            float2 w2 = *reinterpret_cast<const float2*>(wr + 4);
            const float hh[4] = {hv.x, hv.y, hv.z, hv.w};
            const float ww[6] = {w0.x, w0.y, w1.x, w1.y, w2.x, w2.y};
#pragma unroll
            for (int i = 0; i < 4; ++i)
#pragma unroll
                for (int j = 0; j < 6; ++j)
                    acc[i][j] = fmaf(hh[i], ww[j], acc[i][j]);
        }
    }
    __syncthreads();                    // LDS dead -> reuse for writeback

    float (*ob)[NOUT + 1] = reinterpret_cast<float (*)[NOUT + 1]>(smem);
#pragma unroll
    for (int i = 0; i < 4; ++i)
#pragma unroll
        for (int j = 0; j < 6; ++j)
            ob[tg * 4 + i][og * 6 + j] = acc[i][j];
    __syncthreads();

    // coalesced float4 writeback of the 32x192 partial tile
    const size_t base = ((size_t)sl * TOKENS + tok0) * NOUT;
#pragma unroll
    for (int r = 0; r < 6; ++r) {
        int q = tid + 256 * r;          // 0..1535
        int t = q / 48;                 // 0..31
        int c = (q - t * 48) * 4;       // 0..188, mult of 4
        float4 v = {ob[t][c], ob[t][c + 1], ob[t][c + 2], ob[t][c + 3]};
        *reinterpret_cast<float4*>(part + base + (size_t)t * NOUT + c) = v;
    }
}

constexpr int TB2 = 64;                 // tokens per epilogue block

__global__ __launch_bounds__(256) void gates_epilogue(
    const float* __restrict__ part,
    const float* __restrict__ conflict,
    const float* __restrict__ rpb, const float* __restrict__ rhw,
    const float* __restrict__ rhb, const float* __restrict__ gw1,
    const float* __restrict__ gb1, const float* __restrict__ gw2,
    const float* __restrict__ gb2,
    float* __restrict__ coef)
{
    __shared__ float ob[TB2][NOUT + 1];   // 49.4 KB
    const int tid  = threadIdx.x;
    const int tok0 = blockIdx.x * TB2;

    // reduce the 4 K-slice partials (fixed order -> deterministic fp32)
#pragma unroll
    for (int r = 0; r < 12; ++r) {
        int q = tid + 256 * r;          // 0..3071
        int t = q / 48;                 // 0..63
        int c = (q - t * 48) * 4;       // 0..188
        float4 s = {0.f, 0.f, 0.f, 0.f};
#pragma unroll
        for (int sl = 0; sl < NSLICE; ++sl) {
            const float4 v = *reinterpret_cast<const float4*>(
                part + ((size_t)sl * TOKENS + tok0 + t) * NOUT + c);
            s.x += v.x; s.y += v.y; s.z += v.z; s.w += v.w;
        }
        ob[t][c] = s.x; ob[t][c + 1] = s.y; ob[t][c + 2] = s.z; ob[t][c + 3] = s.w;
    }
    __syncthreads();

    if (tid < TB2) {
        const int t  = tid;
        const int gt = tok0 + t;

        // rel = sigmoid(relu(feat) @ rhw + rhb)
        float ra[NA] = {0.f, 0.f, 0.f, 0.f};
        for (int j = 0; j < RH; ++j) {
            float f = ob[t][j] + rpb[j];
            f = f > 0.f ? f : 0.f;
#pragma unroll
            for (int a = 0; a < NA; ++a) ra[a] = fmaf(f, rhw[j * NA + a], ra[a]);
        }
        float rel[NA], cf[NA];
#pragma unroll
        for (int a = 0; a < NA; ++a) {
            rel[a] = 1.f / (1.f + expf(-(ra[a] + rhb[a])));
            cf[a]  = conflict[(size_t)gt * NA + a];
        }

        // hid = relu(hid_pre + rel/conf rows of gate_w1 + b1); logits = hid@gw2+b2
        float lg[6] = {0.f, 0.f, 0.f, 0.f, 0.f, 0.f};
        for (int i = 0; i < HG; ++i) {
            float v = ob[t][RH + i] + gb1[i];
#pragma unroll
            for (int a = 0; a < NA; ++a)
                v = fmaf(rel[a], gw1[(size_t)(D + a) * HG + i], v);
#pragma unroll
            for (int a = 0; a < NA; ++a)
                v = fmaf(cf[a], gw1[(size_t)(D + NA + a) * HG + i], v);
            v = v > 0.f ? v : 0.f;
#pragma unroll
            for (int c = 0; c < 6; ++c) lg[c] = fmaf(v, gw2[i * 6 + c], lg[c]);
        }
#pragma unroll
        for (int c = 0; c < 6; ++c) lg[c] += gb2[c];   // TEMPERATURE == 1

        // top-2 of adapter logits lg[2..5]; strict > keeps lax.top_k tie order
        int i1 = 0;
#pragma unroll
        for (int a = 1; a < NA; ++a) if (lg[2 + a] > lg[2 + i1]) i1 = a;
        int i2 = (i1 == 0) ? 1 : 0;
#pragma unroll
        for (int a = 0; a < NA; ++a)
            if (a != i1 && lg[2 + a] > lg[2 + i2]) i2 = a;

        // softmax over {l0, l1, kept adapters}; dropped adapters are -inf
        float m  = fmaxf(fmaxf(lg[0], lg[1]), fmaxf(lg[2 + i1], lg[2 + i2]));
        float e0 = expf(lg[0] - m), e1 = expf(lg[1] - m);
        float ea = expf(lg[2 + i1] - m), eb = expf(lg[2 + i2] - m);
        float inv = 1.f / (e0 + e1 + ea + eb);

        float out5[5] = {e1 * inv, 0.f, 0.f, 0.f, 0.f};   // gates[...,1]
        out5[1 + i1] = ea * inv;
        out5[1 + i2] = eb * inv;
        float* cp = coef + (size_t)gt * 8;
#pragma unroll
        for (int s = 0; s < 5; ++s) cp[s] = out5[s];
    }
}

__global__ __launch_bounds__(256) void combine_kernel(
    const float* __restrict__ sd,
    const float* __restrict__ ar,
    const float* __restrict__ coef,
    float* __restrict__ out)
{
    const size_t NT4 = (size_t)TOKENS * (D / 4);   // 8,388,608 float4s
    const size_t stride = (size_t)gridDim.x * blockDim.x;
    const float4* sd4  = reinterpret_cast<const float4*>(sd);
    const float4* ar4  = reinterpret_cast<const float4*>(ar);
    float4*       out4 = reinterpret_cast<float4*>(out);

    for (size_t v = (size_t)blockIdx.x * blockDim.x + threadIdx.x;
         v < NT4; v += stride) {
        const int tok = (int)(v >> 10);            // D/4 = 1024 float4s/token
        const float* cp = coef + (size_t)tok * 8;
        const float cs = cp[0];
        float4 s = sd4[v];
        float4 o;
        o.x = cs * s.x; o.y = cs * s.y; o.z = cs * s.z; o.w = cs * s.w;
#pragma unroll
        for (int n = 0; n < NA; ++n) {
            const float cn = cp[1 + n];
            if (cn != 0.f) {                       // uniform per token
                float4 r = ar4[(size_t)n * NT4 + v];
                o.x = fmaf(cn, r.x, o.x); o.y = fmaf(cn, r.y, o.y);
                o.z = fmaf(cn, r.z, o.z); o.w = fmaf(cn, r.w, o.w);
            }
        }
        out4[v] = o;
    }
}

extern "C" void kernel_launch(void* const* d_in, const int* in_sizes, int n_in,
                              void* d_out, int out_size, void* d_ws, size_t ws_size,
                              hipStream_t stream) {
    const float* h   = (const float*)d_in[0];
    const float* sd  = (const float*)d_in[1];
    const float* ar  = (const float*)d_in[2];
    const float* cs  = (const float*)d_in[3];
    const float* rpw = (const float*)d_in[4];
    const float* rpb = (const float*)d_in[5];
    const float* rhw = (const float*)d_in[6];
    const float* rhb = (const float*)d_in[7];
    const float* gw1 = (const float*)d_in[8];
    const float* gb1 = (const float*)d_in[9];
    const float* gw2 = (const float*)d_in[10];
    const float* gb2 = (const float*)d_in[11];

    float* part = (float*)d_out;           // 25.2 MB scratch; combine rewrites
    float* coef = (float*)d_ws;            // 8192 tokens * 8 floats = 256 KB
    float* out  = (float*)d_out;

    hipLaunchKernelGGL(gates_partial, dim3(256 * NSLICE), dim3(256), 0, stream,
                       h, rpw, gw1, part);
    hipLaunchKernelGGL(gates_epilogue, dim3(TOKENS / TB2), dim3(256), 0, stream,
                       part, cs, rpb, rhw, rhb, gw1, gb1, gw2, gb2, coef);
    hipLaunchKernelGGL(combine_kernel, dim3(2048), dim3(256), 0, stream,
                       sd, ar, coef, out);
}

// Round 11
// 1035.102 us; speedup vs baseline: 1.2370x; 1.1543x over previous
//
#include <hip/hip_runtime.h>
#include <math.h>

// ---------------------------------------------------------------------------
// ConflictAwareResidualRouter  (B=4, S=2048, D=4096, H=128, RH=64, NA=4, K=2)
//
// R7 counters (gates_partial): 403us, VALUBusy 33%, Occ 44.8%, VGPR 48,
// WRITE_SIZE 806MB (expected 25MB). Diagnosis: launch_bounds(256,4) made the
// allocator spill the 24-VGPR cross-barrier W-prefetch array to scratch every
// chunk: 96B x 256thr x 32chunks x 1024blocks = 805MB of HBM writes ->
// spill-traffic-bound. Fix: synchronous staging (short live ranges, nothing
// live across barriers) + launch_bounds(256,2). TLP (4-5 blocks/CU) hides
// staging latency instead of register ILP.
//
// gates_partial : per (token-block, k-slice) partial 192-wide GEMM outputs,
//                 written fp32 to d_out scratch (combine overwrites d_out).
// gates_epilogue: sum 4 slices (fixed order), rel/sigmoid, gate MLP, top-2
//                 mask + softmax -> 5 coefs/token into d_ws.
// combine       : out = c_static*sd + sum_n c_n*res_n; 2 of 4 adapters
//                 skipped per token (uniform per wave).
// ---------------------------------------------------------------------------

constexpr int D      = 4096;
constexpr int RH     = 64;
constexpr int HG     = 128;
constexpr int NA     = 4;
constexpr int NOUT   = RH + HG;     // 192
constexpr int TOKENS = 4 * 2048;    // 8192
constexpr int M_BLK  = 32;          // tokens per block
constexpr int NSLICE = 4;           // K slices
constexpr int KSL    = D / NSLICE;  // 1024
constexpr int KC     = 32;          // K chunk
constexpr int NCH    = KSL / KC;    // 32 chunks per slice

__global__ __launch_bounds__(256, 2) void gates_partial(
    const float* __restrict__ h,
    const float* __restrict__ rpw,
    const float* __restrict__ gw1,
    float* __restrict__ part)           // [NSLICE][TOKENS][NOUT] in d_out
{
    __shared__ float smem[KC * M_BLK + KC * NOUT];   // 1024+6144 fl = 28KB
    float* hT = smem;                  // [row=k][col' swizzled], flat 32*32
    float* wT = smem + KC * M_BLK;     // flat [k*192 + col]

    const int tid   = threadIdx.x;
    const int bt    = blockIdx.x >> 2;         // token block 0..255
    const int sl    = blockIdx.x & 3;          // k slice    0..3
    const int tok0  = bt * M_BLK;
    const int kbase = sl * KSL;
    const int tg    = tid & 7;                 // tokens tg*4..tg*4+3
    const int og    = tid >> 3;                // cols og*6..og*6+5

    float acc[4][6];
#pragma unroll
    for (int i = 0; i < 4; ++i)
#pragma unroll
        for (int j = 0; j < 6; ++j) acc[i][j] = 0.f;

    for (int kc = 0; kc < NCH; ++kc) {
        const int k0 = kbase + kc * KC;
        __syncthreads();                // prior compute done reading LDS

        // ---- synchronous staging; all live ranges end before the barrier ---
        // h: 1 float4/thread, 8 lanes span 128B contiguous -> coalesced
        {
            const int tok = tid >> 3, kq = tid & 7;
            const float4 hv = *reinterpret_cast<const float4*>(
                h + (size_t)(tok0 + tok) * D + k0 + kq * 4);
            const float v[4] = {hv.x, hv.y, hv.z, hv.w};
#pragma unroll
            for (int j = 0; j < 4; ++j) {
                const int row = kq * 4 + j;                 // 0..31
                const int col = (tok + 4 * (row & 7)) & 31; // rotation swizzle
                hT[row * M_BLK + col] = v[j];
            }
        }
        // W: 6 float4/thread into flat packed [k][0..191]
        float4 w[6];
#pragma unroll
        for (int r = 0; r < 6; ++r) {
            const int q = tid + 256 * r;       // 0..1535
            const int f = q * 4;               // packed offset
            const int k = f / NOUT;            // magic-mul
            const int c = f - k * NOUT;        // mult of 4; no 64-boundary straddle
            const float* src = (c < RH)
                ? (rpw + (size_t)(k0 + k) * RH + c)
                : (gw1 + (size_t)(k0 + k) * HG + (c - RH));
            w[r] = *reinterpret_cast<const float4*>(src);
        }
#pragma unroll
        for (int r = 0; r < 6; ++r)
            *reinterpret_cast<float4*>(wT + (size_t)(tid + 256 * r) * 4) = w[r];

        __syncthreads();                // tile visible to all waves

#pragma unroll 2
        for (int k = 0; k < KC; ++k) {
            // swizzled, 16B-aligned (base mult of 4, no mod-32 wrap)
            const float4 hv = *reinterpret_cast<const float4*>(
                &hT[k * M_BLK + ((tg * 4 + 4 * (k & 7)) & 31)]);
            const float* wr = wT + k * NOUT + og * 6;
            float2 w0 = *reinterpret_cast<const float2*>(wr + 0);
            float2 w1 = *reinterpret_cast<const float2*>(wr + 2);
            float2 w2 = *reinterpret_cast<const float2*>(wr + 4);
            const float hh[4] = {hv.x, hv.y, hv.z, hv.w};
            const float ww[6] = {w0.x, w0.y, w1.x, w1.y, w2.x, w2.y};
#pragma unroll
            for (int i = 0; i < 4; ++i)
#pragma unroll
                for (int j = 0; j < 6; ++j)
                    acc[i][j] = fmaf(hh[i], ww[j], acc[i][j]);
        }
    }
    __syncthreads();                    // LDS dead -> reuse for writeback

    float (*ob)[NOUT + 1] = reinterpret_cast<float (*)[NOUT + 1]>(smem);
#pragma unroll
    for (int i = 0; i < 4; ++i)
#pragma unroll
        for (int j = 0; j < 6; ++j)
            ob[tg * 4 + i][og * 6 + j] = acc[i][j];
    __syncthreads();

    // coalesced float4 writeback of the 32x192 partial tile
    const size_t base = ((size_t)sl * TOKENS + tok0) * NOUT;
#pragma unroll
    for (int r = 0; r < 6; ++r) {
        int q = tid + 256 * r;          // 0..1535
        int t = q / 48;                 // 0..31
        int c = (q - t * 48) * 4;       // 0..188, mult of 4
        float4 v = {ob[t][c], ob[t][c + 1], ob[t][c + 2], ob[t][c + 3]};
        *reinterpret_cast<float4*>(part + base + (size_t)t * NOUT + c) = v;
    }
}

constexpr int TB2 = 64;                 // tokens per epilogue block

__global__ __launch_bounds__(256) void gates_epilogue(
    const float* __restrict__ part,
    const float* __restrict__ conflict,
    const float* __restrict__ rpb, const float* __restrict__ rhw,
    const float* __restrict__ rhb, const float* __restrict__ gw1,
    const float* __restrict__ gb1, const float* __restrict__ gw2,
    const float* __restrict__ gb2,
    float* __restrict__ coef)
{
    __shared__ float ob[TB2][NOUT + 1];   // 49.4 KB
    const int tid  = threadIdx.x;
    const int tok0 = blockIdx.x * TB2;

    // reduce the 4 K-slice partials (fixed order -> deterministic fp32)
#pragma unroll
    for (int r = 0; r < 12; ++r) {
        int q = tid + 256 * r;          // 0..3071
        int t = q / 48;                 // 0..63
        int c = (q - t * 48) * 4;       // 0..188
        float4 s = {0.f, 0.f, 0.f, 0.f};
#pragma unroll
        for (int sl = 0; sl < NSLICE; ++sl) {
            const float4 v = *reinterpret_cast<const float4*>(
                part + ((size_t)sl * TOKENS + tok0 + t) * NOUT + c);
            s.x += v.x; s.y += v.y; s.z += v.z; s.w += v.w;
        }
        ob[t][c] = s.x; ob[t][c + 1] = s.y; ob[t][c + 2] = s.z; ob[t][c + 3] = s.w;
    }
    __syncthreads();

    if (tid < TB2) {
        const int t  = tid;
        const int gt = tok0 + t;

        // rel = sigmoid(relu(feat) @ rhw + rhb)
        float ra[NA] = {0.f, 0.f, 0.f, 0.f};
        for (int j = 0; j < RH; ++j) {
            float f = ob[t][j] + rpb[j];
            f = f > 0.f ? f : 0.f;
#pragma unroll
            for (int a = 0; a < NA; ++a) ra[a] = fmaf(f, rhw[j * NA + a], ra[a]);
        }
        float rel[NA], cf[NA];
#pragma unroll
        for (int a = 0; a < NA; ++a) {
            rel[a] = 1.f / (1.f + expf(-(ra[a] + rhb[a])));
            cf[a]  = conflict[(size_t)gt * NA + a];
        }

        // hid = relu(hid_pre + rel/conf rows of gate_w1 + b1); logits = hid@gw2+b2
        float lg[6] = {0.f, 0.f, 0.f, 0.f, 0.f, 0.f};
        for (int i = 0; i < HG; ++i) {
            float v = ob[t][RH + i] + gb1[i];
#pragma unroll
            for (int a = 0; a < NA; ++a)
                v = fmaf(rel[a], gw1[(size_t)(D + a) * HG + i], v);
#pragma unroll
            for (int a = 0; a < NA; ++a)
                v = fmaf(cf[a], gw1[(size_t)(D + NA + a) * HG + i], v);
            v = v > 0.f ? v : 0.f;
#pragma unroll
            for (int c = 0; c < 6; ++c) lg[c] = fmaf(v, gw2[i * 6 + c], lg[c]);
        }
#pragma unroll
        for (int c = 0; c < 6; ++c) lg[c] += gb2[c];   // TEMPERATURE == 1

        // top-2 of adapter logits lg[2..5]; strict > keeps lax.top_k tie order
        int i1 = 0;
#pragma unroll
        for (int a = 1; a < NA; ++a) if (lg[2 + a] > lg[2 + i1]) i1 = a;
        int i2 = (i1 == 0) ? 1 : 0;
#pragma unroll
        for (int a = 0; a < NA; ++a)
            if (a != i1 && lg[2 + a] > lg[2 + i2]) i2 = a;

        // softmax over {l0, l1, kept adapters}; dropped adapters are -inf
        float m  = fmaxf(fmaxf(lg[0], lg[1]), fmaxf(lg[2 + i1], lg[2 + i2]));
        float e0 = expf(lg[0] - m), e1 = expf(lg[1] - m);
        float ea = expf(lg[2 + i1] - m), eb = expf(lg[2 + i2] - m);
        float inv = 1.f / (e0 + e1 + ea + eb);

        float out5[5] = {e1 * inv, 0.f, 0.f, 0.f, 0.f};   // gates[...,1]
        out5[1 + i1] = ea * inv;
        out5[1 + i2] = eb * inv;
        float* cp = coef + (size_t)gt * 8;
#pragma unroll
        for (int s = 0; s < 5; ++s) cp[s] = out5[s];
    }
}

__global__ __launch_bounds__(256) void combine_kernel(
    const float* __restrict__ sd,
    const float* __restrict__ ar,
    const float* __restrict__ coef,
    float* __restrict__ out)
{
    const size_t NT4 = (size_t)TOKENS * (D / 4);   // 8,388,608 float4s
    const size_t stride = (size_t)gridDim.x * blockDim.x;
    const float4* sd4  = reinterpret_cast<const float4*>(sd);
    const float4* ar4  = reinterpret_cast<const float4*>(ar);
    float4*       out4 = reinterpret_cast<float4*>(out);

    for (size_t v = (size_t)blockIdx.x * blockDim.x + threadIdx.x;
         v < NT4; v += stride) {
        const int tok = (int)(v >> 10);            // D/4 = 1024 float4s/token
        const float* cp = coef + (size_t)tok * 8;
        const float cs = cp[0];
        float4 s = sd4[v];
        float4 o;
        o.x = cs * s.x; o.y = cs * s.y; o.z = cs * s.z; o.w = cs * s.w;
#pragma unroll
        for (int n = 0; n < NA; ++n) {
            const float cn = cp[1 + n];
            if (cn != 0.f) {                       // uniform per token
                float4 r = ar4[(size_t)n * NT4 + v];
                o.x = fmaf(cn, r.x, o.x); o.y = fmaf(cn, r.y, o.y);
                o.z = fmaf(cn, r.z, o.z); o.w = fmaf(cn, r.w, o.w);
            }
        }
        out4[v] = o;
    }
}

extern "C" void kernel_launch(void* const* d_in, const int* in_sizes, int n_in,
                              void* d_out, int out_size, void* d_ws, size_t ws_size,
                              hipStream_t stream) {
    const float* h   = (const float*)d_in[0];
    const float* sd  = (const float*)d_in[1];
    const float* ar  = (const float*)d_in[2];
    const float* cs  = (const float*)d_in[3];
    const float* rpw = (const float*)d_in[4];
    const float* rpb = (const float*)d_in[5];
    const float* rhw = (const float*)d_in[6];
    const float* rhb = (const float*)d_in[7];
    const float* gw1 = (const float*)d_in[8];
    const float* gb1 = (const float*)d_in[9];
    const float* gw2 = (const float*)d_in[10];
    const float* gb2 = (const float*)d_in[11];

    float* part = (float*)d_out;           // 25.2 MB scratch; combine rewrites
    float* coef = (float*)d_ws;            // 8192 tokens * 8 floats = 256 KB
    float* out  = (float*)d_out;

    hipLaunchKernelGGL(gates_partial, dim3(256 * NSLICE), dim3(256), 0, stream,
                       h, rpw, gw1, part);
    hipLaunchKernelGGL(gates_epilogue, dim3(TOKENS / TB2), dim3(256), 0, stream,
                       part, cs, rpb, rhw, rhb, gw1, gb1, gw2, gb2, coef);
    hipLaunchKernelGGL(combine_kernel, dim3(2048), dim3(256), 0, stream,
                       sd, ar, coef, out);
}